// Round 1
// baseline (1361.344 us; speedup 1.0000x reference)
//
#include <hip/hip_runtime.h>

#define Bn  32
#define Nn  12000
#define Tn  20000
#define N1n 4000
#define N2n 1000
#define NXn 5000   // N1+N2

// ---------------- helpers ----------------

// Batch-modified point coords (pre-y-correction): returns (c0, c1, c2)
__device__ __forceinline__ float3 fetch_pt(int i, int b,
    const float* __restrict__ x, const float* __restrict__ y,
    const float* __restrict__ pz)
{
  if (i < N1n) {
    const float* p = x + (size_t)b * (N1n * 3) + i * 3;
    return make_float3(p[0], p[1], p[2]);
  } else if (i < NXn) {
    const float* p = y + (size_t)b * (N2n * 2) + (i - N1n) * 2;
    return make_float3(p[0], pz[3 * i + 1], p[1]);   // c0=y0, c1=pz.y, c2=y1
  } else {
    return make_float3(pz[3 * i], pz[3 * i + 1], pz[3 * i + 2]);
  }
}

// Coords (c0, c1) with y-correction applied to c1 for i < N1
__device__ __forceinline__ float2 fetch_pt01(int i, int b,
    const float* __restrict__ x, const float* __restrict__ y,
    const float* __restrict__ pz, const float* __restrict__ coeffy, float fyb)
{
  if (i < N1n) {
    const float* p = x + (size_t)b * (N1n * 3) + i * 3;
    return make_float2(p[0], p[1] + coeffy[(size_t)b * N1n + i] * fyb);
  } else if (i < NXn) {
    const float* p = y + (size_t)b * (N2n * 2) + (i - N1n) * 2;
    return make_float2(p[0], pz[3 * i + 1]);
  } else {
    return make_float2(pz[3 * i], pz[3 * i + 1]);
  }
}

// ---------------- K1: dy (t-major [t][b]) + per-batch volume + vol_const ----------------
__global__ void k_dy_vol(const float* __restrict__ x, const float* __restrict__ y,
    const float* __restrict__ pz, const int* __restrict__ tri,
    float* __restrict__ dyT, float* __restrict__ vol, float* __restrict__ volc)
{
  const int tid = threadIdx.x;
  const int b  = tid & 31;
  const int tl = tid >> 5;           // 0..7
  float accV = 0.f, accC = 0.f;
  for (int t = blockIdx.x * 8 + tl; t < Tn; t += gridDim.x * 8) {
    const int i0 = tri[3 * t], i1 = tri[3 * t + 1], i2 = tri[3 * t + 2];
    float3 p0 = fetch_pt(i0, b, x, y, pz);
    float3 p1 = fetch_pt(i1, b, x, y, pz);
    float3 p2 = fetch_pt(i2, b, x, y, pz);
    float dy = ((p0.x - p1.x) * (p2.z - p1.z) - (p0.z - p1.z) * (p2.x - p1.x)) * (1.0f / 6.0f);
    dyT[(size_t)t * 32 + b] = dy;
    accV += (p0.y + p1.y + p2.y) * dy;
    if (b == 0) {  // zero-geometry volume (vol_const)
      float3 q0 = make_float3(pz[3 * i0], pz[3 * i0 + 1], pz[3 * i0 + 2]);
      float3 q1 = make_float3(pz[3 * i1], pz[3 * i1 + 1], pz[3 * i1 + 2]);
      float3 q2 = make_float3(pz[3 * i2], pz[3 * i2 + 1], pz[3 * i2 + 2]);
      float dy0 = ((q0.x - q1.x) * (q2.z - q1.z) - (q0.z - q1.z) * (q2.x - q1.x)) * (1.0f / 6.0f);
      accC += (q0.y + q1.y + q2.y) * dy0;
    }
  }
  __shared__ float red[256];
  red[tid] = accV;
  __syncthreads();
  if (tl == 0) {
    float s = accV;
    #pragma unroll
    for (int q = 1; q < 8; ++q) s += red[q * 32 + b];
    atomicAdd(&vol[b], s);
  }
  __syncthreads();
  red[tid] = accC;
  __syncthreads();
  if (tid == 0) {
    float s = 0.f;
    #pragma unroll
    for (int q = 0; q < 8; ++q) s += red[q * 32];
    atomicAdd(volc, s);
  }
}

// ---------------- K3: dz (t-major) with corrected y ----------------
__global__ void k_dz(const float* __restrict__ x, const float* __restrict__ y,
    const float* __restrict__ pz, const int* __restrict__ tri,
    const float* __restrict__ coeffy, const float* __restrict__ fy,
    float* __restrict__ dzT)
{
  const int tid = threadIdx.x;
  const int b  = tid & 31;
  const int tl = tid >> 5;
  const float fyb = fy[b];
  for (int t = blockIdx.x * 8 + tl; t < Tn; t += gridDim.x * 8) {
    const int i0 = tri[3 * t], i1 = tri[3 * t + 1], i2 = tri[3 * t + 2];
    float2 p0 = fetch_pt01(i0, b, x, y, pz, coeffy, fyb);
    float2 p1 = fetch_pt01(i1, b, x, y, pz, coeffy, fyb);
    float2 p2 = fetch_pt01(i2, b, x, y, pz, coeffy, fyb);
    float dz = ((p0.x - p2.x) * (p1.y - p2.y) - (p0.y - p2.y) * (p1.x - p2.x)) * (1.0f / 6.0f);
    dzT[(size_t)t * 32 + b] = dz;
  }
}

// ---------------- split-K GEMM: C[b][j] += sum_t A[t][b] * V[j][t] ----------------
// block: 128 threads; tile 32b x 256j; KT=32; thread tile 8b x 8j
#define KT     32
#define JT     256
#define SVS    260      // padded LDS stride for sB
#define KCHUNK 640

__global__ __launch_bounds__(128, 2)
void k_gemm(const float* __restrict__ A,   // [Tn][32] t-major
            const float* __restrict__ V,   // [NJ][Tn]
            float* __restrict__ C,         // [Bn][NJ]
            int NJ)
{
  __shared__ float sA[KT * 32];
  __shared__ float sB[KT * SVS];
  const int tid = threadIdx.x;
  const int t0 = blockIdx.x * KCHUNK;
  const int t1 = min(t0 + KCHUNK, Tn);
  const int jb = blockIdx.y * JT;
  const int tb = tid & 3;        // 4 b-groups of 8
  const int tj = tid >> 2;       // 32 j-groups of 8
  const int rrow = tid >> 3;     // 0..15 (staging row)
  const int tc4  = (tid & 7) * 4;

  float acc[8][8];
  #pragma unroll
  for (int i = 0; i < 8; ++i)
    #pragma unroll
    for (int j = 0; j < 8; ++j) acc[i][j] = 0.f;

  for (int tk = t0; tk < t1; tk += KT) {
    __syncthreads();
    // stage A: 32t x 32b = 1024 floats, contiguous
    {
      float4 a0 = *(const float4*)(A + (size_t)tk * 32 + tid * 8);
      float4 a1 = *(const float4*)(A + (size_t)tk * 32 + tid * 8 + 4);
      *(float4*)(sA + tid * 8)     = a0;
      *(float4*)(sA + tid * 8 + 4) = a1;
    }
    // stage B transposed: sB[k][j], 256 rows x 32 t (128B per row from global)
    #pragma unroll
    for (int p = 0; p < 16; ++p) {
      int r  = p * 16 + rrow;
      int jg = jb + r;
      float4 v = make_float4(0.f, 0.f, 0.f, 0.f);
      if (jg < NJ) v = *(const float4*)(V + (size_t)jg * Tn + tk + tc4);
      sB[(tc4 + 0) * SVS + r] = v.x;
      sB[(tc4 + 1) * SVS + r] = v.y;
      sB[(tc4 + 2) * SVS + r] = v.z;
      sB[(tc4 + 3) * SVS + r] = v.w;
    }
    __syncthreads();
    #pragma unroll 4
    for (int kk = 0; kk < KT; ++kk) {
      float4 a0 = *(const float4*)(sA + kk * 32 + tb * 8);
      float4 a1 = *(const float4*)(sA + kk * 32 + tb * 8 + 4);
      float4 b0 = *(const float4*)(sB + kk * SVS + tj * 8);
      float4 b1 = *(const float4*)(sB + kk * SVS + tj * 8 + 4);
      const float av[8] = {a0.x, a0.y, a0.z, a0.w, a1.x, a1.y, a1.z, a1.w};
      const float bv[8] = {b0.x, b0.y, b0.z, b0.w, b1.x, b1.y, b1.z, b1.w};
      #pragma unroll
      for (int i = 0; i < 8; ++i)
        #pragma unroll
        for (int j = 0; j < 8; ++j)
          acc[i][j] += av[i] * bv[j];
    }
  }
  // epilogue: split-K combine via fp32 atomics
  #pragma unroll
  for (int i = 0; i < 8; ++i) {
    int b = tb * 8 + i;
    #pragma unroll
    for (int j = 0; j < 8; ++j) {
      int jg = jb + tj * 8 + j;
      if (jg < NJ) atomicAdd(&C[(size_t)b * NJ + jg], acc[i][j]);
    }
  }
}

// ---------------- K2/K4: s = sum coeff^2 ; factor = a / s ----------------
__global__ void k_factor(const float* __restrict__ coeff, int NJ,
    const float* __restrict__ vol, const float* __restrict__ volc,
    float* __restrict__ aArr, float* __restrict__ factor, int computeA)
{
  const int b = blockIdx.x;
  float s = 0.f;
  for (int j = threadIdx.x; j < NJ; j += 256) {
    float v = coeff[(size_t)b * NJ + j];
    s += v * v;
  }
  __shared__ float red[256];
  red[threadIdx.x] = s;
  __syncthreads();
  for (int off = 128; off; off >>= 1) {
    if (threadIdx.x < off) red[threadIdx.x] += red[threadIdx.x + off];
    __syncthreads();
  }
  if (threadIdx.x == 0) {
    float a;
    if (computeA) { a = 0.5f * (volc[0] - vol[b]); aArr[b] = a; }
    else          { a = aArr[b]; }
    factor[b] = a / red[0];
  }
}

// ---------------- K5: assemble outputs ----------------
// out1: [32][4000][3] at offset 0 (384000), out2: [32][1000][2] at 384000 (64000)
__global__ void k_out(const float* __restrict__ x, const float* __restrict__ y,
    const float* __restrict__ coeffy, const float* __restrict__ coeffz,
    const float* __restrict__ fy, const float* __restrict__ fz,
    float* __restrict__ out)
{
  int idx = blockIdx.x * blockDim.x + threadIdx.x;
  if (idx >= 448000) return;
  if (idx < 384000) {
    int b = idx / 12000;
    int r = idx - b * 12000;
    int i = r / 3, c = r - i * 3;
    float v = x[(size_t)b * 12000 + r];
    if (c == 1)      v += coeffy[(size_t)b * N1n + i] * fy[b];
    else if (c == 2) v += coeffz[(size_t)b * NXn + i] * fz[b];
    out[idx] = v;
  } else {
    int k = idx - 384000;
    int b = k / 2000;
    int r = k - b * 2000;
    int i = r >> 1, c = r & 1;
    float v = y[(size_t)b * 2000 + r];
    if (c) v += coeffz[(size_t)b * NXn + N1n + i] * fz[b];
    out[idx] = v;
  }
}

// ---------------- launch ----------------
extern "C" void kernel_launch(void* const* d_in, const int* in_sizes, int n_in,
                              void* d_out, int out_size, void* d_ws, size_t ws_size,
                              hipStream_t stream)
{
  const float* x   = (const float*)d_in[0];
  const float* y   = (const float*)d_in[1];
  const float* pz  = (const float*)d_in[2];
  const int*   tri = (const int*)d_in[3];
  // d_in[4], d_in[5] are arange indices (layout is known; unused)
  const float* Vx  = (const float*)d_in[6];   // [N1][T]
  const float* Vxy = (const float*)d_in[7];   // [N1+N2][T]
  float* out = (float*)d_out;

  float* ws     = (float*)d_ws;
  float* dyT    = ws;                 // 640000 floats  [t][b]
  float* dzT    = ws + 640000;        // 640000
  float* coeffy = ws + 1280000;       // 128000  [b][j]
  float* coeffz = ws + 1408000;       // 160000
  float* vol    = ws + 1568000;       // 32
  float* volc   = ws + 1568032;       // 1
  float* aArr   = ws + 1568064;       // 32
  float* fy     = ws + 1568096;       // 32
  float* fz     = ws + 1568128;       // 32

  // zero the atomic-accumulated region (coeffy, coeffz, vol, volc)
  hipMemsetAsync(coeffy, 0, (size_t)288064 * sizeof(float), stream);

  k_dy_vol<<<256, 256, 0, stream>>>(x, y, pz, tri, dyT, vol, volc);
  k_gemm<<<dim3(32, 16), 128, 0, stream>>>(dyT, Vx, coeffy, N1n);
  k_factor<<<32, 256, 0, stream>>>(coeffy, N1n, vol, volc, aArr, fy, 1);
  k_dz<<<256, 256, 0, stream>>>(x, y, pz, tri, coeffy, fy, dzT);
  k_gemm<<<dim3(32, 20), 128, 0, stream>>>(dzT, Vxy, coeffz, NXn);
  k_factor<<<32, 256, 0, stream>>>(coeffz, NXn, vol, volc, aArr, fz, 0);
  k_out<<<(448000 + 255) / 256, 256, 0, stream>>>(x, y, coeffy, coeffz, fy, fz, out);
}